// Round 1
// baseline (1390.061 us; speedup 1.0000x reference)
//
#include <hip/hip_runtime.h>
#include <stdint.h>

// BitLinear: x[4,2048,4096] fp32, w[16384,4096] fp32 -> out[4,2048,16384] fp32
// M = 8192 tokens, N = 16384, K = 4096.
// Exact int8 path: C = s_m * gamma * (int8 dot ternary), i32 accum exact.

#define M_DIM 8192
#define N_DIM 16384
#define K_DIM 4096
#define W_ELEMS (N_DIM * K_DIM)   // 67108864
#define X_ELEMS (M_DIM * K_DIM)   // 33554432

typedef int v4i __attribute__((ext_vector_type(4)));

// workspace layout (bytes)
#define WS_GSUM   0u            // double
#define WS_SCALES 256u          // float[8192]
#define WS_XQ     65536u        // int8[M][K] = 33554432 B
#define WS_WQ     33685504u     // int8[N][K] = 67108864 B  (total ~96.1 MiB)

// ---------------- gamma = max(mean |w|, 1e-6) ----------------
__global__ __launch_bounds__(256) void k_gamma(const float4* __restrict__ w,
                                               double* __restrict__ gsum) {
    int tid = blockIdx.x * 256 + threadIdx.x;
    int stride = gridDim.x * 256;
    float s = 0.f;
    for (int i = tid; i < W_ELEMS / 4; i += stride) {
        float4 v = w[i];
        s += fabsf(v.x) + fabsf(v.y) + fabsf(v.z) + fabsf(v.w);
    }
    #pragma unroll
    for (int off = 32; off; off >>= 1) s += __shfl_down(s, off, 64);
    __shared__ float wsum[4];
    int lane = threadIdx.x & 63, wv = threadIdx.x >> 6;
    if (lane == 0) wsum[wv] = s;
    __syncthreads();
    if (threadIdx.x == 0) {
        double t = (double)wsum[0] + (double)wsum[1] + (double)wsum[2] + (double)wsum[3];
        atomicAdd(gsum, t);
    }
}

__device__ __forceinline__ int pack4i8(float a, float b, float c, float d) {
    int ia = (int)a & 0xFF, ib = (int)b & 0xFF, ic = (int)c & 0xFF, id = (int)d & 0xFF;
    return ia | (ib << 8) | (ic << 16) | (id << 24);
}

// ---------------- wq = round(clip(w/gamma, -1, 1)) as int8 ----------------
__global__ __launch_bounds__(256) void k_wq(const float4* __restrict__ w,
                                            const double* __restrict__ gsum,
                                            int* __restrict__ wq4) {
    float g = fmaxf((float)(*gsum * (1.0 / 67108864.0)), 1e-6f);
    int tid = blockIdx.x * 256 + threadIdx.x;
    int stride = gridDim.x * 256;
    for (int i = tid; i < W_ELEMS / 4; i += stride) {
        float4 v = w[i];
        float qa = rintf(fminf(fmaxf(v.x / g, -1.f), 1.f));
        float qb = rintf(fminf(fmaxf(v.y / g, -1.f), 1.f));
        float qc = rintf(fminf(fmaxf(v.z / g, -1.f), 1.f));
        float qd = rintf(fminf(fmaxf(v.w / g, -1.f), 1.f));
        wq4[i] = pack4i8(qa, qb, qc, qd);
    }
}

// ---------------- per-token act quant ----------------
__global__ __launch_bounds__(256) void k_xq(const float4* __restrict__ x,
                                            int* __restrict__ xq4,
                                            float* __restrict__ scales) {
    int token = blockIdx.x;
    int t = threadIdx.x;
    const float4* xrow = x + (size_t)token * (K_DIM / 4);
    float4 v[4];
    float m = 0.f;
    #pragma unroll
    for (int i = 0; i < 4; i++) {
        v[i] = xrow[i * 256 + t];
        m = fmaxf(m, fmaxf(fmaxf(fabsf(v[i].x), fabsf(v[i].y)),
                           fmaxf(fabsf(v[i].z), fabsf(v[i].w))));
    }
    #pragma unroll
    for (int off = 32; off; off >>= 1) m = fmaxf(m, __shfl_xor(m, off, 64));
    __shared__ float wm[4];
    int lane = t & 63, wv = t >> 6;
    if (lane == 0) wm[wv] = m;
    __syncthreads();
    m = fmaxf(fmaxf(wm[0], wm[1]), fmaxf(wm[2], wm[3]));
    float s = fmaxf(m / 127.0f, 1e-8f);
    int* orow = xq4 + (size_t)token * (K_DIM / 4);
    #pragma unroll
    for (int i = 0; i < 4; i++) {
        float qa = fminf(fmaxf(rintf(v[i].x / s), -127.f), 127.f);
        float qb = fminf(fmaxf(rintf(v[i].y / s), -127.f), 127.f);
        float qc = fminf(fmaxf(rintf(v[i].z / s), -127.f), 127.f);
        float qd = fminf(fmaxf(rintf(v[i].w / s), -127.f), 127.f);
        orow[i * 256 + t] = pack4i8(qa, qb, qc, qd);
    }
    if (t == 0) scales[token] = s;
}

// ---------------- i8 GEMM, 128x128 tile, BK=64, mfma_i32_16x16x64_i8 ----------------
#define ASYNC_CP16(g, l)                                                              \
    __builtin_amdgcn_global_load_lds((const __attribute__((address_space(1))) void*)(g), \
                                     (__attribute__((address_space(3))) void*)(l), 16, 0, 0)

__global__ __launch_bounds__(256) void k_gemm(const char* __restrict__ A,
                                              const char* __restrict__ B,
                                              const float* __restrict__ scales,
                                              const double* __restrict__ gsum,
                                              float* __restrict__ C) {
    __shared__ char As[128 * 64];
    __shared__ char Bs[128 * 64];
    const int t = threadIdx.x;
    const int m0 = blockIdx.y * 128;
    const int n0 = blockIdx.x * 128;

    // staging: 512 16B chunks per tile; thread t handles chunks t and t+256.
    // LDS dest for chunk c is c*16 -> per wave: uniform base + lane*16 (HW constraint).
    const char* aA0 = A + (size_t)(m0 + (t >> 2)) * K_DIM + (t & 3) * 16;
    const char* aA1 = A + (size_t)(m0 + 64 + (t >> 2)) * K_DIM + (t & 3) * 16;
    const char* aB0 = B + (size_t)(n0 + (t >> 2)) * K_DIM + (t & 3) * 16;
    const char* aB1 = B + (size_t)(n0 + 64 + (t >> 2)) * K_DIM + (t & 3) * 16;
    char* lA0 = &As[t * 16];
    char* lA1 = &As[4096 + t * 16];
    char* lB0 = &Bs[t * 16];
    char* lB1 = &Bs[4096 + t * 16];

    v4i acc[4][4];
    #pragma unroll
    for (int i = 0; i < 4; i++)
        #pragma unroll
        for (int j = 0; j < 4; j++) {
            v4i z = {0, 0, 0, 0};
            acc[i][j] = z;
        }

    const int lane = t & 63;
    const int wv = t >> 6;
    const int qm = (wv >> 1) * 64;   // wave's 64x64 quadrant
    const int qn = (wv & 1) * 64;
    const int r16 = lane & 15;
    const int kq = lane >> 4;        // 0..3: which 16-byte k-slice

    for (int kk = 0; kk < K_DIM; kk += 64) {
        ASYNC_CP16(aA0 + kk, lA0);
        ASYNC_CP16(aA1 + kk, lA1);
        ASYNC_CP16(aB0 + kk, lB0);
        ASYNC_CP16(aB1 + kk, lB1);
        __syncthreads();
        v4i af[4], bf[4];
        #pragma unroll
        for (int i = 0; i < 4; i++)
            af[i] = *(const v4i*)&As[(qm + i * 16 + r16) * 64 + kq * 16];
        #pragma unroll
        for (int j = 0; j < 4; j++)
            bf[j] = *(const v4i*)&Bs[(qn + j * 16 + r16) * 64 + kq * 16];
        #pragma unroll
        for (int i = 0; i < 4; i++)
            #pragma unroll
            for (int j = 0; j < 4; j++)
                acc[i][j] = __builtin_amdgcn_mfma_i32_16x16x64_i8(af[i], bf[j], acc[i][j], 0, 0, 0);
        __syncthreads();
    }

    float gamma = fmaxf((float)(*gsum * (1.0 / 67108864.0)), 1e-6f);
    // C/D layout: col = lane&15, row = (lane>>4)*4 + reg  (dtype-independent, verified)
    #pragma unroll
    for (int i = 0; i < 4; i++) {
        #pragma unroll
        for (int r = 0; r < 4; r++) {
            int grow = m0 + qm + i * 16 + kq * 4 + r;
            float sv = scales[grow] * gamma;
            #pragma unroll
            for (int j = 0; j < 4; j++) {
                int gcol = n0 + qn + j * 16 + r16;
                C[(size_t)grow * N_DIM + gcol] = sv * (float)acc[i][j][r];
            }
        }
    }
}

extern "C" void kernel_launch(void* const* d_in, const int* in_sizes, int n_in,
                              void* d_out, int out_size, void* d_ws, size_t ws_size,
                              hipStream_t stream) {
    const float* x = (const float*)d_in[0];
    const float* w = (const float*)d_in[1];
    float* out = (float*)d_out;
    char* ws = (char*)d_ws;

    double* gsum = (double*)(ws + WS_GSUM);
    float* scales = (float*)(ws + WS_SCALES);
    char* xq = ws + WS_XQ;
    char* wq = ws + WS_WQ;

    hipMemsetAsync(gsum, 0, sizeof(double), stream);
    k_gamma<<<2048, 256, 0, stream>>>((const float4*)w, gsum);
    k_wq<<<4096, 256, 0, stream>>>((const float4*)w, gsum, (int*)wq);
    k_xq<<<M_DIM, 256, 0, stream>>>((const float4*)x, (int*)xq, scales);
    k_gemm<<<dim3(N_DIM / 128, M_DIM / 128), 256, 0, stream>>>(xq, wq, scales, gsum, out);
}